// Round 5
// baseline (188.056 us; speedup 1.0000x reference)
//
#include <hip/hip_runtime.h>
#include <hip/hip_bf16.h>

#define NPAIR 4096
#define DIM   768
#define N2    8192
#define BM    128            // tile is 128x128; 4 waves as 2x2 of 64x64
#define KBLK  64
#define KITER (DIM / KBLK)   // 12
#define NT    (N2 / BM)      // 64 block-rows
#define NTILES (NT * (NT + 1) / 2)   // 2080 upper-triangle tiles

constexpr float INV_T = 1.0f / 0.07f;  // also the fixed softmax max M

typedef __bf16 bf16x8 __attribute__((ext_vector_type(8)));
typedef float  f32x16 __attribute__((ext_vector_type(16)));

__device__ inline unsigned short f2bf(float x) {
    return __builtin_bit_cast(unsigned short, (__bf16)x);
}

// ---------------- normalize: one wave per row, fp32 in -> bf16 out ----------
__global__ void knorm(const float* __restrict__ z1, const float* __restrict__ z2,
                      unsigned short* __restrict__ zb) {
    const int row  = blockIdx.x * 4 + (threadIdx.x >> 6);
    const int lane = threadIdx.x & 63;
    const float* src = (row < NPAIR) ? (z1 + (size_t)row * DIM)
                                     : (z2 + (size_t)(row - NPAIR) * DIM);
    float4 v[3];
    float ss = 0.f;
#pragma unroll
    for (int i = 0; i < 3; ++i) {
        v[i] = reinterpret_cast<const float4*>(src)[lane + 64 * i];
        ss += v[i].x * v[i].x + v[i].y * v[i].y + v[i].z * v[i].z + v[i].w * v[i].w;
    }
#pragma unroll
    for (int off = 32; off; off >>= 1) ss += __shfl_xor(ss, off);
    const float scale = 1.0f / fmaxf(sqrtf(ss), 1e-12f);
    ushort4* dst = reinterpret_cast<ushort4*>(zb + (size_t)row * DIM);
#pragma unroll
    for (int i = 0; i < 3; ++i) {
        ushort4 o;
        o.x = f2bf(v[i].x * scale); o.y = f2bf(v[i].y * scale);
        o.z = f2bf(v[i].z * scale); o.w = f2bf(v[i].w * scale);
        dst[lane + 64 * i] = o;
    }
}

// ---------------- positive-pair dots: one wave per pair ---------------------
__global__ void kpos(const unsigned short* __restrict__ zb, float* __restrict__ pos) {
    const int pair = blockIdx.x * 4 + (threadIdx.x >> 6);
    const int lane = threadIdx.x & 63;
    const bf16x8* a = reinterpret_cast<const bf16x8*>(zb + (size_t)pair * DIM);
    const bf16x8* b = reinterpret_cast<const bf16x8*>(zb + (size_t)(pair + NPAIR) * DIM);
    float s = 0.f;
#pragma unroll
    for (int c = 0; c < 2; ++c) {
        const int idx = lane + 64 * c;
        if (idx < 96) {
            bf16x8 va = a[idx], vb = b[idx];
#pragma unroll
            for (int j = 0; j < 8; ++j) s += (float)va[j] * (float)vb[j];
        }
    }
#pragma unroll
    for (int off = 32; off; off >>= 1) s += __shfl_xor(s, off);
    if (lane == 0) pos[pair] = s * INV_T;
}

// ---------------- main: upper-triangle tiles, double-buffered pipeline ------
// One block per 128x128 tile (bi<=cj). Wave = 64x64 via 2x2 of
// mfma_f32_32x32x16_bf16. A/B K-tiles double-buffered in LDS (64KB) with
// counted vmcnt(8) so next-tile loads stay in flight across barriers.
// Off-diag tiles credit rowsum[rows] and rowsum[cols] (symmetry, 2x saving).
__global__ __launch_bounds__(256) void klse(const unsigned short* __restrict__ zb,
                                            float* __restrict__ rowsum) {
    __shared__ __align__(16) unsigned short As[2][BM * KBLK];  // 2 x 16 KB
    __shared__ __align__(16) unsigned short Bs[2][BM * KBLK];  // 2 x 16 KB
    const int tid  = threadIdx.x;
    const int wave = tid >> 6;
    const int lane = tid & 63;
    const int wr = wave >> 1, wc = wave & 1;
    const int hi = lane >> 5, rlo = lane & 31;

    // tile index -> (bi, cj) in upper triangle; XCD-chunked swizzle (2080=8*260)
    int t = blockIdx.x;
    t = (t & 7) * (NTILES / 8) + (t >> 3);
    int bi = (int)((129.0f - sqrtf(16641.0f - 8.0f * (float)t)) * 0.5f);
    while ((bi + 1) * (2 * NT - bi) / 2 <= t) ++bi;
    while (bi * (2 * NT - bi + 1) / 2 > t) --bi;
    const int cj = bi + (t - bi * (2 * NT - bi + 1) / 2);
    const int rb = bi * BM, c0 = cj * BM;
    const bool diag = (cj == bi);

    const int sw  = rlo & 7;
    const int raA = (wr * 64 + rlo) * KBLK;
    const int raB = raA + 32 * KBLK;
    const int caA = (wc * 64 + rlo) * KBLK;
    const int caB = caA + 32 * KBLK;

    f32x16 acc00 = {}, acc01 = {}, acc10 = {}, acc11 = {};

    auto stage = [&](int kt, int buf) {
#pragma unroll
        for (int i = 0; i < 4; ++i) {
            const int g = i * 256 + tid;       // 16B granule
            const int r = g >> 3, slot = g & 7;
            const int ksrc = kt * KBLK + ((slot ^ (r & 7)) << 3);
            const unsigned short* srcA = zb + (size_t)(rb + r) * DIM + ksrc;
            const unsigned short* srcB = zb + (size_t)(c0 + r) * DIM + ksrc;
            __builtin_amdgcn_global_load_lds(
                (const __attribute__((address_space(1))) unsigned int*)srcA,
                (__attribute__((address_space(3))) unsigned int*)(&As[buf][g * 8]),
                16, 0, 0);
            __builtin_amdgcn_global_load_lds(
                (const __attribute__((address_space(1))) unsigned int*)srcB,
                (__attribute__((address_space(3))) unsigned int*)(&Bs[buf][g * 8]),
                16, 0, 0);
        }
    };

    stage(0, 0);
    for (int kt = 0; kt < KITER; ++kt) {
        const int cur = kt & 1;
        if (kt + 1 < KITER) {
            stage(kt + 1, cur ^ 1);                       // prefetch next K-tile
            asm volatile("s_waitcnt vmcnt(8)" ::: "memory");  // cur tile landed
        } else {
            asm volatile("s_waitcnt vmcnt(0)" ::: "memory");
        }
        __builtin_amdgcn_s_barrier();
        asm volatile("" ::: "memory");
#pragma unroll
        for (int tt = 0; tt < 4; ++tt) {
            const int ko = tt * 2 + hi;
            const int so = (ko ^ sw) << 3;
            bf16x8 a0 = *reinterpret_cast<const bf16x8*>(&As[cur][raA + so]);
            bf16x8 a1 = *reinterpret_cast<const bf16x8*>(&As[cur][raB + so]);
            bf16x8 b0 = *reinterpret_cast<const bf16x8*>(&Bs[cur][caA + so]);
            bf16x8 b1 = *reinterpret_cast<const bf16x8*>(&Bs[cur][caB + so]);
            acc00 = __builtin_amdgcn_mfma_f32_32x32x16_bf16(a0, b0, acc00, 0, 0, 0);
            acc01 = __builtin_amdgcn_mfma_f32_32x32x16_bf16(a0, b1, acc01, 0, 0, 0);
            acc10 = __builtin_amdgcn_mfma_f32_32x32x16_bf16(a1, b0, acc10, 0, 0, 0);
            acc11 = __builtin_amdgcn_mfma_f32_32x32x16_bf16(a1, b1, acc11, 0, 0, 0);
        }
        asm volatile("" ::: "memory");
        __builtin_amdgcn_s_barrier();   // reads done before next prefetch overwrites
    }

    // ---------------- epilogue: exp, mask, row+col credits ------------------
    const int row0b = rb + wr * 64 + 4 * hi;
    const int colg  = c0 + wc * 64 + rlo;
    float ps0[16], ps1[16];
    float cs0 = 0.f, cs1 = 0.f;
#pragma unroll
    for (int r = 0; r < 16; ++r) {
        const int rg0 = row0b + (r & 3) + 8 * (r >> 2);
        float e00 = __expf((acc00[r] - 1.0f) * INV_T);
        float e01 = __expf((acc01[r] - 1.0f) * INV_T);
        float e10 = __expf((acc10[r] - 1.0f) * INV_T);
        float e11 = __expf((acc11[r] - 1.0f) * INV_T);
        if (diag) {
            if (rg0 == colg)           e00 = 0.f;
            if (rg0 == colg + 32)      e01 = 0.f;
            if (rg0 + 32 == colg)      e10 = 0.f;
            if (rg0 + 32 == colg + 32) e11 = 0.f;
        }
        ps0[r] = e00 + e01;
        ps1[r] = e10 + e11;
        cs0 += e00 + e10;
        cs1 += e01 + e11;
    }
    // row-side: reduce across the 32 col-lanes of each half
#pragma unroll
    for (int r = 0; r < 16; ++r) {
#pragma unroll
        for (int m = 1; m < 32; m <<= 1) {
            ps0[r] += __shfl_xor(ps0[r], m);
            ps1[r] += __shfl_xor(ps1[r], m);
        }
    }
    if (rlo == 0) {
#pragma unroll
        for (int r = 0; r < 16; ++r) {
            const int rg0 = row0b + (r & 3) + 8 * (r >> 2);
            atomicAdd(&rowsum[rg0], ps0[r]);
            atomicAdd(&rowsum[rg0 + 32], ps1[r]);
        }
    }
    // col-side (off-diag only): fold hi halves, one atomic per column
    if (!diag) {
        cs0 += __shfl_xor(cs0, 32);
        cs1 += __shfl_xor(cs1, 32);
        if (hi == 0) {
            atomicAdd(&rowsum[colg], cs0);
            atomicAdd(&rowsum[colg + 32], cs1);
        }
    }
}

// ---------------- final: loss = mean(M + log S_i - pos) ---------------------
__global__ void kfinal(const float* __restrict__ rowsum, const float* __restrict__ pos,
                       float* __restrict__ out) {
    __shared__ float red[8];
    const int tid = threadIdx.x;
    float s = 0.f;
    for (int i = tid; i < N2; i += 512) {
        const int p = (i < NPAIR) ? i : i - NPAIR;
        s += INV_T + __logf(rowsum[i]) - pos[p];
    }
#pragma unroll
    for (int off = 32; off; off >>= 1) s += __shfl_xor(s, off);
    if ((tid & 63) == 0) red[tid >> 6] = s;
    __syncthreads();
    if (tid == 0) {
        float t = 0.f;
#pragma unroll
        for (int w = 0; w < 8; ++w) t += red[w];
        out[0] = t / (float)N2;
    }
}

extern "C" void kernel_launch(void* const* d_in, const int* in_sizes, int n_in,
                              void* d_out, int out_size, void* d_ws, size_t ws_size,
                              hipStream_t stream) {
    const float* z1 = (const float*)d_in[0];
    const float* z2 = (const float*)d_in[1];
    unsigned short* zb = (unsigned short*)d_ws;                       // 8192*768 bf16
    float* rowsum = (float*)((char*)d_ws + (size_t)N2 * DIM * 2);     // 8192 f32
    float* pos = rowsum + N2;                                         // 4096 f32
    float* out = (float*)d_out;

    hipLaunchKernelGGL(knorm, dim3(N2 / 4), dim3(256), 0, stream, z1, z2, zb);
    hipLaunchKernelGGL(kpos, dim3(NPAIR / 4), dim3(256), 0, stream, zb, pos);
    hipMemsetAsync(rowsum, 0, N2 * sizeof(float), stream);
    hipLaunchKernelGGL(klse, dim3(NTILES), dim3(256), 0, stream, zb, rowsum);
    hipLaunchKernelGGL(kfinal, dim3(1), dim3(512), 0, stream, rowsum, pos, out);
}

// Round 6
// 187.455 us; speedup vs baseline: 1.0032x; 1.0032x over previous
//
#include <hip/hip_runtime.h>
#include <hip/hip_bf16.h>

#define NPAIR 4096
#define DIM   768
#define N2    8192
#define BM    128            // tile is 128x128; 4 waves as 2x2 of 64x64
#define KBLK  64
#define KITER (DIM / KBLK)   // 12
#define NT    (N2 / BM)      // 64 block-rows
#define NTILES (NT * (NT + 1) / 2)   // 2080 upper-triangle tiles

constexpr float INV_T = 1.0f / 0.07f;  // also the fixed softmax max M

typedef __bf16 bf16x8 __attribute__((ext_vector_type(8)));
typedef float  f32x16 __attribute__((ext_vector_type(16)));

__device__ inline unsigned short f2bf(float x) {
    return __builtin_bit_cast(unsigned short, (__bf16)x);
}

// ---------------- normalize: one wave per row, fp32 in -> bf16 out ----------
__global__ void knorm(const float* __restrict__ z1, const float* __restrict__ z2,
                      unsigned short* __restrict__ zb) {
    const int row  = blockIdx.x * 4 + (threadIdx.x >> 6);
    const int lane = threadIdx.x & 63;
    const float* src = (row < NPAIR) ? (z1 + (size_t)row * DIM)
                                     : (z2 + (size_t)(row - NPAIR) * DIM);
    float4 v[3];
    float ss = 0.f;
#pragma unroll
    for (int i = 0; i < 3; ++i) {
        v[i] = reinterpret_cast<const float4*>(src)[lane + 64 * i];
        ss += v[i].x * v[i].x + v[i].y * v[i].y + v[i].z * v[i].z + v[i].w * v[i].w;
    }
#pragma unroll
    for (int off = 32; off; off >>= 1) ss += __shfl_xor(ss, off);
    const float scale = 1.0f / fmaxf(sqrtf(ss), 1e-12f);
    ushort4* dst = reinterpret_cast<ushort4*>(zb + (size_t)row * DIM);
#pragma unroll
    for (int i = 0; i < 3; ++i) {
        ushort4 o;
        o.x = f2bf(v[i].x * scale); o.y = f2bf(v[i].y * scale);
        o.z = f2bf(v[i].z * scale); o.w = f2bf(v[i].w * scale);
        dst[lane + 64 * i] = o;
    }
}

// ---------------- positive-pair dots: one wave per pair ---------------------
__global__ void kpos(const unsigned short* __restrict__ zb, float* __restrict__ pos) {
    const int pair = blockIdx.x * 4 + (threadIdx.x >> 6);
    const int lane = threadIdx.x & 63;
    const bf16x8* a = reinterpret_cast<const bf16x8*>(zb + (size_t)pair * DIM);
    const bf16x8* b = reinterpret_cast<const bf16x8*>(zb + (size_t)(pair + NPAIR) * DIM);
    float s = 0.f;
#pragma unroll
    for (int c = 0; c < 2; ++c) {
        const int idx = lane + 64 * c;
        if (idx < 96) {
            bf16x8 va = a[idx], vb = b[idx];
#pragma unroll
            for (int j = 0; j < 8; ++j) s += (float)va[j] * (float)vb[j];
        }
    }
#pragma unroll
    for (int off = 32; off; off >>= 1) s += __shfl_xor(s, off);
    if (lane == 0) pos[pair] = s * INV_T;
}

// ---------------- main: upper-triangle tiles, double-buffered pipeline ------
// One block per 128x128 tile (bi<=cj). Wave = 64x64 via 2x2 of
// mfma_f32_32x32x16_bf16. A/B K-tiles double-buffered in LDS (64KB) with
// counted vmcnt(8) so next-tile loads stay in flight across barriers.
// Off-diag tiles credit rowsum[rows] and rowsum[cols] (symmetry, 2x saving).
__global__ __launch_bounds__(256) void klse(const unsigned short* __restrict__ zb,
                                            float* __restrict__ rowsum) {
    __shared__ __align__(16) unsigned short As[2][BM * KBLK];  // 2 x 16 KB
    __shared__ __align__(16) unsigned short Bs[2][BM * KBLK];  // 2 x 16 KB
    const int tid  = threadIdx.x;
    const int wave = tid >> 6;
    const int lane = tid & 63;
    const int wr = wave >> 1, wc = wave & 1;
    const int hi = lane >> 5, rlo = lane & 31;

    // tile index -> (bi, cj) in upper triangle; XCD-chunked swizzle (2080=8*260)
    int t = blockIdx.x;
    t = (t & 7) * (NTILES / 8) + (t >> 3);
    int bi = (int)((129.0f - sqrtf(16641.0f - 8.0f * (float)t)) * 0.5f);
    while ((bi + 1) * (2 * NT - bi) / 2 <= t) ++bi;
    while (bi * (2 * NT - bi + 1) / 2 > t) --bi;
    const int cj = bi + (t - bi * (2 * NT - bi + 1) / 2);
    const int rb = bi * BM, c0 = cj * BM;
    const bool diag = (cj == bi);

    const int sw  = rlo & 7;
    const int raA = (wr * 64 + rlo) * KBLK;
    const int raB = raA + 32 * KBLK;
    const int caA = (wc * 64 + rlo) * KBLK;
    const int caB = caA + 32 * KBLK;

    f32x16 acc00 = {}, acc01 = {}, acc10 = {}, acc11 = {};

    auto stage = [&](int kt, int buf) {
#pragma unroll
        for (int i = 0; i < 4; ++i) {
            const int g = i * 256 + tid;       // 16B granule
            const int r = g >> 3, slot = g & 7;
            const int ksrc = kt * KBLK + ((slot ^ (r & 7)) << 3);
            const unsigned short* srcA = zb + (size_t)(rb + r) * DIM + ksrc;
            const unsigned short* srcB = zb + (size_t)(c0 + r) * DIM + ksrc;
            __builtin_amdgcn_global_load_lds(
                (const __attribute__((address_space(1))) unsigned int*)srcA,
                (__attribute__((address_space(3))) unsigned int*)(&As[buf][g * 8]),
                16, 0, 0);
            __builtin_amdgcn_global_load_lds(
                (const __attribute__((address_space(1))) unsigned int*)srcB,
                (__attribute__((address_space(3))) unsigned int*)(&Bs[buf][g * 8]),
                16, 0, 0);
        }
    };

    stage(0, 0);
    for (int kt = 0; kt < KITER; ++kt) {
        const int cur = kt & 1;
        if (kt + 1 < KITER) {
            stage(kt + 1, cur ^ 1);                       // prefetch next K-tile
            asm volatile("s_waitcnt vmcnt(8)" ::: "memory");  // cur tile landed
        } else {
            asm volatile("s_waitcnt vmcnt(0)" ::: "memory");
        }
        __builtin_amdgcn_s_barrier();
        asm volatile("" ::: "memory");
#pragma unroll
        for (int tt = 0; tt < 4; ++tt) {
            const int ko = tt * 2 + hi;
            const int so = (ko ^ sw) << 3;
            bf16x8 a0 = *reinterpret_cast<const bf16x8*>(&As[cur][raA + so]);
            bf16x8 a1 = *reinterpret_cast<const bf16x8*>(&As[cur][raB + so]);
            bf16x8 b0 = *reinterpret_cast<const bf16x8*>(&Bs[cur][caA + so]);
            bf16x8 b1 = *reinterpret_cast<const bf16x8*>(&Bs[cur][caB + so]);
            acc00 = __builtin_amdgcn_mfma_f32_32x32x16_bf16(a0, b0, acc00, 0, 0, 0);
            acc01 = __builtin_amdgcn_mfma_f32_32x32x16_bf16(a0, b1, acc01, 0, 0, 0);
            acc10 = __builtin_amdgcn_mfma_f32_32x32x16_bf16(a1, b0, acc10, 0, 0, 0);
            acc11 = __builtin_amdgcn_mfma_f32_32x32x16_bf16(a1, b1, acc11, 0, 0, 0);
        }
        asm volatile("" ::: "memory");
        __builtin_amdgcn_s_barrier();   // reads done before next prefetch overwrites
    }

    // ---------------- epilogue: exp, mask, row+col credits ------------------
    const int row0b = rb + wr * 64 + 4 * hi;
    const int colg  = c0 + wc * 64 + rlo;
    float ps0[16], ps1[16];
    float cs0 = 0.f, cs1 = 0.f;
#pragma unroll
    for (int r = 0; r < 16; ++r) {
        const int rg0 = row0b + (r & 3) + 8 * (r >> 2);
        float e00 = __expf((acc00[r] - 1.0f) * INV_T);
        float e01 = __expf((acc01[r] - 1.0f) * INV_T);
        float e10 = __expf((acc10[r] - 1.0f) * INV_T);
        float e11 = __expf((acc11[r] - 1.0f) * INV_T);
        if (diag) {
            if (rg0 == colg)           e00 = 0.f;
            if (rg0 == colg + 32)      e01 = 0.f;
            if (rg0 + 32 == colg)      e10 = 0.f;
            if (rg0 + 32 == colg + 32) e11 = 0.f;
        }
        ps0[r] = e00 + e01;
        ps1[r] = e10 + e11;
        cs0 += e00 + e10;
        cs1 += e01 + e11;
    }
    // row-side: reduce across the 32 col-lanes of each half
#pragma unroll
    for (int r = 0; r < 16; ++r) {
#pragma unroll
        for (int m = 1; m < 32; m <<= 1) {
            ps0[r] += __shfl_xor(ps0[r], m);
            ps1[r] += __shfl_xor(ps1[r], m);
        }
    }
    if (rlo == 0) {
#pragma unroll
        for (int r = 0; r < 16; ++r) {
            const int rg0 = row0b + (r & 3) + 8 * (r >> 2);
            atomicAdd(&rowsum[rg0], ps0[r]);
            atomicAdd(&rowsum[rg0 + 32], ps1[r]);
        }
    }
    // col-side (off-diag only): fold hi halves, one atomic per column
    if (!diag) {
        cs0 += __shfl_xor(cs0, 32);
        cs1 += __shfl_xor(cs1, 32);
        if (hi == 0) {
            atomicAdd(&rowsum[colg], cs0);
            atomicAdd(&rowsum[colg + 32], cs1);
        }
    }
}

// ---------------- final: loss = mean(M + log S_i - pos) ---------------------
__global__ void kfinal(const float* __restrict__ rowsum, const float* __restrict__ pos,
                       float* __restrict__ out) {
    __shared__ float red[8];
    const int tid = threadIdx.x;
    float s = 0.f;
    for (int i = tid; i < N2; i += 512) {
        const int p = (i < NPAIR) ? i : i - NPAIR;
        s += INV_T + __logf(rowsum[i]) - pos[p];
    }
#pragma unroll
    for (int off = 32; off; off >>= 1) s += __shfl_xor(s, off);
    if ((tid & 63) == 0) red[tid >> 6] = s;
    __syncthreads();
    if (tid == 0) {
        float t = 0.f;
#pragma unroll
        for (int w = 0; w < 8; ++w) t += red[w];
        out[0] = t / (float)N2;
    }
}

extern "C" void kernel_launch(void* const* d_in, const int* in_sizes, int n_in,
                              void* d_out, int out_size, void* d_ws, size_t ws_size,
                              hipStream_t stream) {
    const float* z1 = (const float*)d_in[0];
    const float* z2 = (const float*)d_in[1];
    unsigned short* zb = (unsigned short*)d_ws;                       // 8192*768 bf16
    float* rowsum = (float*)((char*)d_ws + (size_t)N2 * DIM * 2);     // 8192 f32
    float* pos = rowsum + N2;                                         // 4096 f32
    float* out = (float*)d_out;

    hipLaunchKernelGGL(knorm, dim3(N2 / 4), dim3(256), 0, stream, z1, z2, zb);
    hipLaunchKernelGGL(kpos, dim3(NPAIR / 4), dim3(256), 0, stream, zb, pos);
    hipMemsetAsync(rowsum, 0, N2 * sizeof(float), stream);
    hipLaunchKernelGGL(klse, dim3(NTILES), dim3(256), 0, stream, zb, rowsum);
    hipLaunchKernelGGL(kfinal, dim3(1), dim3(512), 0, stream, rowsum, pos, out);
}